// Round 13
// baseline (55.847 us; speedup 1.0000x reference)
//
#include <hip/hip_runtime.h>
#include <math.h>

// Problem constants (match reference)
static constexpr int Bn  = 256;   // batch
static constexpr int Dd  = 2048;  // feature dim
static constexpr int ATT = 512;   // attribute dim
static constexpr int Cc  = 1024;  // classes
static constexpr int SK1 = 8;     // split-K slices GEMM1 (K=2048, chunk 256)
static constexpr int SK2 = 4;     // split-K slices GEMM2 (K=512,  chunk 128)
static constexpr int BM = 128, BN = 64, BK = 32;
static constexpr int AP = 40;     // LDS row pitch in halfwords (80B; <=2-way bank alias)
// TEMP=4 -> 1/TEMP=0.25, TEMP^2=16 ; SCALE=20 ; SCALE/TEMP=5

typedef __attribute__((ext_vector_type(8))) short short8v;  // 8 bf16 (MFMA A/B frag)
typedef __attribute__((ext_vector_type(4))) float f32x4;    // MFMA C/D frag

// ---------------- reductions (blockDim.x == 256) ----------------
__device__ __forceinline__ float wave_reduce_sum(float v) {
#pragma unroll
    for (int off = 32; off; off >>= 1) v += __shfl_down(v, off, 64);
    return v;
}
__device__ __forceinline__ float wave_reduce_max(float v) {
#pragma unroll
    for (int off = 32; off; off >>= 1) v = fmaxf(v, __shfl_down(v, off, 64));
    return v;
}
__device__ __forceinline__ float block_reduce_sum(float v) {
    __shared__ float sm_s[4];
    v = wave_reduce_sum(v);
    __syncthreads();                 // protect sm_s reuse across calls
    if ((threadIdx.x & 63) == 0) sm_s[threadIdx.x >> 6] = v;
    __syncthreads();
    return sm_s[0] + sm_s[1] + sm_s[2] + sm_s[3];
}
__device__ __forceinline__ float block_reduce_max(float v) {
    __shared__ float sm_m[4];
    v = wave_reduce_max(v);
    __syncthreads();
    if ((threadIdx.x & 63) == 0) sm_m[threadIdx.x >> 6] = v;
    __syncthreads();
    return fmaxf(fmaxf(sm_m[0], sm_m[1]), fmaxf(sm_m[2], sm_m[3]));
}

// ---------------- f32 -> bf16 hi/lo split (truncation; lo = next 8 mantissa bits)
__device__ __forceinline__ void splitbf(float v, unsigned short& h, unsigned short& l) {
    const unsigned int b = __float_as_uint(v);
    h = (unsigned short)(b >> 16);
    const float r = v - __uint_as_float(b & 0xFFFF0000u);
    l = (unsigned short)(__float_as_uint(r) >> 16);
}

// ---- K0: pre-split x and W into hi/lo bf16 (one float4 per thread)
__global__ __launch_bounds__(256) void k0_split(const float* __restrict__ x,
                                                const float* __restrict__ W,
                                                unsigned short* __restrict__ xh,
                                                unsigned short* __restrict__ xl,
                                                unsigned short* __restrict__ wh,
                                                unsigned short* __restrict__ wl) {
    const float* src; unsigned short *dh, *dl; int idx;
    if (blockIdx.x < 512) {                       // x: 131072 float4
        src = x; dh = xh; dl = xl; idx = blockIdx.x * 256 + threadIdx.x;
    } else {                                      // W: 262144 float4
        src = W; dh = wh; dl = wl; idx = (blockIdx.x - 512) * 256 + threadIdx.x;
    }
    const float4 v = ((const float4*)src)[idx];
    unsigned short h0, h1, h2, h3, l0, l1, l2, l3;
    splitbf(v.x, h0, l0); splitbf(v.y, h1, l1);
    splitbf(v.z, h2, l2); splitbf(v.w, h3, l3);
    *(ushort4*)(dh + (size_t)idx * 4) = make_ushort4(h0, h1, h2, h3);
    *(ushort4*)(dl + (size_t)idx * 4) = make_ushort4(l0, l1, l2, l3);
}

// ------- split-bf16 MFMA 128x64 tile from PRE-SPLIT bf16 operands.
// 3 MFMA terms (hi*hi + hi*lo + lo*hi), f32 acc -> ~2^-17 rel error.
// Staging: pure ushort8 load -> ds_write_b128 (no VALU split), reg prefetch.
// Frag layout (m92/m89-verified): A/B lane l: row/col l&15, k-group (l>>4)*8;
// D: col=lane&15, row=(lane>>4)*4+reg.
__device__ __forceinline__ void gemm_tile_bf(const unsigned short* __restrict__ Ah,
                                             const unsigned short* __restrict__ Al,
                                             const unsigned short* __restrict__ Bh,
                                             const unsigned short* __restrict__ Bl,
                                             float* __restrict__ dst, int N, int K,
                                             int row0, int col0, int kbase, int kc,
                                             unsigned short* __restrict__ LAh,
                                             unsigned short* __restrict__ LAl,
                                             unsigned short* __restrict__ LBh,
                                             unsigned short* __restrict__ LBl) {
    const int tid = threadIdx.x;
    const int lane = tid & 63, wv = tid >> 6;
    const int fr = lane & 15, fg = lane >> 4;
    const int ar = tid >> 2, ac8 = (tid & 3) * 8;   // 64 rows x 4 ushort8 per stage step

    short8v pah0, pah1, pal0, pal1, pbh0, pbl0;
    #define LDG(p, r, kk) (*(const short8v*)((p) + (size_t)(r) * K + (kk)))
    pah0 = LDG(Ah, row0 + ar, kbase + ac8);  pah1 = LDG(Ah, row0 + 64 + ar, kbase + ac8);
    pal0 = LDG(Al, row0 + ar, kbase + ac8);  pal1 = LDG(Al, row0 + 64 + ar, kbase + ac8);
    pbh0 = LDG(Bh, col0 + ar, kbase + ac8);  pbl0 = LDG(Bl, col0 + ar, kbase + ac8);

    f32x4 acc[2][4] = {};
    for (int k0 = kbase; k0 < kbase + kc; k0 += BK) {
        __syncthreads();                     // LDS reuse guard
        *(short8v*)(LAh + ar * AP + ac8) = pah0;
        *(short8v*)(LAh + (64 + ar) * AP + ac8) = pah1;
        *(short8v*)(LAl + ar * AP + ac8) = pal0;
        *(short8v*)(LAl + (64 + ar) * AP + ac8) = pal1;
        *(short8v*)(LBh + ar * AP + ac8) = pbh0;
        *(short8v*)(LBl + ar * AP + ac8) = pbl0;
        __syncthreads();
        if (k0 + BK < kbase + kc) {          // prefetch next K-tile
            const int kn = k0 + BK + ac8;
            pah0 = LDG(Ah, row0 + ar, kn);  pah1 = LDG(Ah, row0 + 64 + ar, kn);
            pal0 = LDG(Al, row0 + ar, kn);  pal1 = LDG(Al, row0 + 64 + ar, kn);
            pbh0 = LDG(Bh, col0 + ar, kn);  pbl0 = LDG(Bl, col0 + ar, kn);
        }
        short8v ah[2], al[2];
#pragma unroll
        for (int im = 0; im < 2; ++im) {
            const int mrow = (wv * 2 + im) * 16 + fr;
            ah[im] = *(short8v*)(LAh + mrow * AP + fg * 8);
            al[im] = *(short8v*)(LAl + mrow * AP + fg * 8);
        }
#pragma unroll
        for (int in = 0; in < 4; ++in) {
            const int nrow = in * 16 + fr;
            const short8v bh = *(short8v*)(LBh + nrow * AP + fg * 8);
            const short8v bl = *(short8v*)(LBl + nrow * AP + fg * 8);
#pragma unroll
            for (int im = 0; im < 2; ++im) {
                acc[im][in] = __builtin_amdgcn_mfma_f32_16x16x32_bf16(ah[im], bh, acc[im][in], 0, 0, 0);
                acc[im][in] = __builtin_amdgcn_mfma_f32_16x16x32_bf16(ah[im], bl, acc[im][in], 0, 0, 0);
                acc[im][in] = __builtin_amdgcn_mfma_f32_16x16x32_bf16(al[im], bh, acc[im][in], 0, 0, 0);
            }
        }
    }
    #undef LDG
#pragma unroll
    for (int im = 0; im < 2; ++im)
#pragma unroll
        for (int in = 0; in < 4; ++in)
#pragma unroll
            for (int r = 0; r < 4; ++r) {
                const int m = row0 + (wv * 2 + im) * 16 + fg * 4 + r;
                const int c = col0 + in * 16 + fr;
                dst[(size_t)m * N + c] = acc[im][in][r];
            }
}

// ---- K1: bid<128 -> GEMM1 split-K tile (8x2x8); bid in [128,384) -> sa=split(l2norm(seen))
__global__ __launch_bounds__(256, 2) void k1_gemm1_sanorm(const unsigned short* __restrict__ xh,
                                                          const unsigned short* __restrict__ xl,
                                                          const unsigned short* __restrict__ wh,
                                                          const unsigned short* __restrict__ wl,
                                                          const float* __restrict__ seen,
                                                          float* __restrict__ part,
                                                          unsigned short* __restrict__ sah,
                                                          unsigned short* __restrict__ sal,
                                                          int* __restrict__ doneCnt) {
    __shared__ unsigned short LAh[BM * AP], LAl[BM * AP];
    __shared__ unsigned short LBh[BN * AP], LBl[BN * AP];
    const int bid = blockIdx.x, tid = threadIdx.x;
    if (bid < 128) {
        const int bx = bid & 7, by = (bid >> 3) & 1, bz = bid >> 4;   // 8 x 2 x 8
        gemm_tile_bf(xh, xl, wh, wl, part + (size_t)bz * Bn * ATT, ATT, Dd,
                     by * BM, bx * BN, bz * (Dd / SK1), Dd / SK1, LAh, LAl, LBh, LBl);
    } else {
        if (bid == 128 && tid == 0) *doneCnt = 0;   // reset k5 completion counter
#pragma unroll
        for (int u = 0; u < 4; ++u) {
            const int r = (bid - 128) * 4 + u, c = tid * 2;
            const float2 v = *(const float2*)(seen + (size_t)r * ATT + c);
            float ss = block_reduce_sum(fmaf(v.x, v.x, v.y * v.y));
            const float sc = 1.0f / fmaxf(sqrtf(ss), 1e-12f);
            unsigned short h0, h1, l0, l1;
            splitbf(v.x * sc, h0, l0); splitbf(v.y * sc, h1, l1);
            *(ushort2*)(sah + (size_t)r * ATT + c) = make_ushort2(h0, h1);
            *(ushort2*)(sal + (size_t)r * ATT + c) = make_ushort2(l0, l1);
        }
    }
}

// ---- K2: ya = split(l2norm(bias + sum_z part1[z][m][:]))  (block per row)
__global__ __launch_bounds__(256) void k2_yanorm(const float* __restrict__ part,
                                                 const float* __restrict__ bias,
                                                 unsigned short* __restrict__ yah,
                                                 unsigned short* __restrict__ yal) {
    const int m = blockIdx.x, c = threadIdx.x * 2;
    float2 s = *(const float2*)(bias + c);
#pragma unroll
    for (int z = 0; z < SK1; ++z) {
        const float2 p = *(const float2*)(part + (size_t)z * Bn * ATT + (size_t)m * ATT + c);
        s.x += p.x; s.y += p.y;
    }
    float ss = block_reduce_sum(fmaf(s.x, s.x, s.y * s.y));
    const float sc = 1.0f / fmaxf(sqrtf(ss), 1e-12f);
    unsigned short h0, h1, l0, l1;
    splitbf(s.x * sc, h0, l0); splitbf(s.y * sc, h1, l1);
    *(ushort2*)(yah + (size_t)m * ATT + c) = make_ushort2(h0, h1);
    *(ushort2*)(yal + (size_t)m * ATT + c) = make_ushort2(l0, l1);
}

// ---- K3: GEMM2 split-K (16 x 2 x 4 = 128 blocks, KC=128)
__global__ __launch_bounds__(256, 2) void k3_gemm2(const unsigned short* __restrict__ yah,
                                                   const unsigned short* __restrict__ yal,
                                                   const unsigned short* __restrict__ sah,
                                                   const unsigned short* __restrict__ sal,
                                                   float* __restrict__ part) {
    __shared__ unsigned short LAh[BM * AP], LAl[BM * AP];
    __shared__ unsigned short LBh[BN * AP], LBl[BN * AP];
    const int bid = blockIdx.x;
    const int bx = bid & 15, by = (bid >> 4) & 1, bz = bid >> 5;   // 16 x 2 x 4
    gemm_tile_bf(yah, yal, sah, sal, part + (size_t)bz * Bn * Cc, Cc, ATT,
                 by * BM, bx * BN, bz * (ATT / SK2), ATT / SK2, LAh, LAl, LBh, LBl);
}

// ---- K4: logits = 5*sum_z part2 ; softmax -> P, negH  (block per row)
__global__ __launch_bounds__(256) void k4_softmax(const float* __restrict__ part,
                                                  float* __restrict__ P,
                                                  float* __restrict__ negH) {
    const int i = blockIdx.x, c = threadIdx.x * 4;
    float4 a = make_float4(0.f, 0.f, 0.f, 0.f);
#pragma unroll
    for (int z = 0; z < SK2; ++z) {
        const float4 p = *(const float4*)(part + (size_t)z * Bn * Cc + (size_t)i * Cc + c);
        a.x += p.x; a.y += p.y; a.z += p.z; a.w += p.w;
    }
    float lv[4] = {a.x * 5.0f, a.y * 5.0f, a.z * 5.0f, a.w * 5.0f};
    float lm = fmaxf(fmaxf(lv[0], lv[1]), fmaxf(lv[2], lv[3]));
    lm = block_reduce_max(lm);
    float se = 0.f;
#pragma unroll
    for (int k = 0; k < 4; ++k) se += __expf(lv[k] - lm);
    se = block_reduce_sum(se);
    const float logZ = __logf(se);
    float nh = 0.f;
    float4 pv;
#pragma unroll
    for (int k = 0; k < 4; ++k) {
        const float lp = lv[k] - lm - logZ;
        const float p = __expf(lp);
        (&pv.x)[k] = p;
        nh = fmaf(p, lp, nh);
    }
    *(float4*)(P + (size_t)i * Cc + c) = pv;
    nh = block_reduce_sum(nh);
    if (threadIdx.x == 0) negH[i] = nh;
}

// ---- K5: JS over masked pairs (block per row, ONE deferred reduction) +
//          last-block finalize via done-counter.
__global__ __launch_bounds__(256) void k5_pairjs_fin(const float* __restrict__ P,
                                                     const float* __restrict__ negH,
                                                     const int* __restrict__ labels,
                                                     float* __restrict__ pairSum,
                                                     float* __restrict__ pairCnt,
                                                     int* __restrict__ doneCnt,
                                                     float* __restrict__ out) {
    const int i = blockIdx.x, tid = threadIdx.x;
    __shared__ int lbl[Bn];
    __shared__ float nh_s[Bn];
    __shared__ int isLast;
    lbl[tid] = labels[tid];
    nh_s[tid] = negH[tid];
    __syncthreads();
    const int li = lbl[i];
    const float4 pi = *(const float4*)(P + (size_t)i * Cc + tid * 4);
    const float nhi = nh_s[i];

    float tsum = 0.f;                 // per-thread cross-term over ALL pairs
    float nsum = 0.f, cnt = 0.f;      // tid 0 bookkeeping
    for (int j = i + 1; j < Bn; ++j) {
        if (lbl[j] != li) continue;   // uniform across block
        const float4 pj = *(const float4*)(P + (size_t)j * Cc + tid * 4);
        float t;
        t = pi.x + pj.x; tsum = fmaf(t, __logf(0.5f * t), tsum);
        t = pi.y + pj.y; tsum = fmaf(t, __logf(0.5f * t), tsum);
        t = pi.z + pj.z; tsum = fmaf(t, __logf(0.5f * t), tsum);
        t = pi.w + pj.w; tsum = fmaf(t, __logf(0.5f * t), tsum);
        if (tid == 0) { nsum += nhi + nh_s[j]; cnt += 1.0f; }
    }
    const float s = block_reduce_sum(tsum);       // ONE reduction for the row
    if (tid == 0) {
        pairSum[i] = 0.5f * (nsum - s);
        pairCnt[i] = cnt;
        __threadfence();                          // publish before signaling
        isLast = (atomicAdd(doneCnt, 1) == Bn - 1);
    }
    __syncthreads();
    if (isLast) {
        __threadfence();                          // acquire others' results
        float fs = block_reduce_sum(pairSum[tid]);
        __syncthreads();
        const float fc = block_reduce_sum(pairCnt[tid]);
        if (tid == 0) out[0] = (fc == 0.0f) ? 0.0f : (fs / fc) * 16.0f;  // * TEMP^2
    }
}

extern "C" void kernel_launch(void* const* d_in, const int* in_sizes, int n_in,
                              void* d_out, int out_size, void* d_ws, size_t ws_size,
                              hipStream_t stream) {
    const float* x      = (const float*)d_in[0];  // [256, 2048]
    const int*   labels = (const int*)d_in[1];    // [256]
    const float* W      = (const float*)d_in[2];  // [512, 2048]
    const float* bias   = (const float*)d_in[3];  // [512]
    const float* seen   = (const float*)d_in[4];  // [1024, 512]
    float* out = (float*)d_out;

    char* ws = (char*)d_ws;
    float*          part = (float*)(ws);                         // 4 MB (both GEMMs)
    unsigned short* xh   = (unsigned short*)(ws + (4u << 20));   // 1 MB
    unsigned short* xl   = (unsigned short*)(ws + (5u << 20));   // 1 MB
    unsigned short* wh   = (unsigned short*)(ws + (6u << 20));   // 2 MB
    unsigned short* wl   = (unsigned short*)(ws + (8u << 20));   // 2 MB
    unsigned short* sah  = (unsigned short*)(ws + (10u << 20));  // 1 MB
    unsigned short* sal  = (unsigned short*)(ws + (11u << 20));  // 1 MB
    unsigned short* yah  = (unsigned short*)(ws + (12u << 20));  // 256 KB
    unsigned short* yal  = (unsigned short*)(ws + (12u << 20) + (256u << 10));
    float*          P    = (float*)(ws + (13u << 20));           // 1 MB
    float*          negH = (float*)(ws + (14u << 20));           // 256 f32
    float* pairSum = negH + Bn;                                  // 256 f32
    float* pairCnt = pairSum + Bn;                               // 256 f32
    int*   doneCnt = (int*)(pairCnt + Bn);                       // 1 int

    k0_split<<<1536, 256, 0, stream>>>(x, W, xh, xl, wh, wl);
    k1_gemm1_sanorm<<<384, 256, 0, stream>>>(xh, xl, wh, wl, seen, part, sah, sal, doneCnt);
    k2_yanorm<<<Bn, 256, 0, stream>>>(part, bias, yah, yal);
    k3_gemm2<<<128, 256, 0, stream>>>(yah, yal, sah, sal, part);
    k4_softmax<<<Bn, 256, 0, stream>>>(part, P, negH);
    k5_pairjs_fin<<<Bn, 256, 0, stream>>>(P, negH, labels, pairSum, pairCnt, doneCnt, out);
}